// Round 9
// baseline (509.967 us; speedup 1.0000x reference)
//
#include <hip/hip_runtime.h>
#include <hip/hip_cooperative_groups.h>
#include <math.h>

namespace cg = cooperative_groups;

#define N_NODES 20000
#define N_EDGES 320000
#define E_TOT   (N_EDGES + N_NODES)
#define C_IN  256
#define C_HID 256
#define C_OUT 128
#define NEG_SLOPE 0.2f

typedef __attribute__((ext_vector_type(8))) short bf16x8;
typedef __attribute__((ext_vector_type(4))) float f32x4;

// ---- all scratch in module globals (ws_size unknown; globals are safe) ----
// weights packed in MFMA-fragment order: idx = ((kt*(Nc/16)+ntile)*64 + kgrp*16+col%16)*8 + k%8
__device__ __align__(16) unsigned short c_W1h[C_IN * C_HID], c_W1l[C_IN * C_HID];
__device__ __align__(16) unsigned short c_W2h[C_HID * C_OUT], c_W2l[C_HID * C_OUT];
__device__ float c_as1f[C_HID], c_ad1f[C_HID], c_b1f[C_HID];
__device__ float c_as2f[C_OUT], c_ad2f[C_OUT], c_b2f[C_OUT];
__device__ __align__(16) unsigned short g_h1b[(size_t)N_NODES * C_HID]; // h1 bf16
__device__ __align__(16) unsigned short g_g1h[(size_t)N_NODES * C_HID]; // relu(agg1) hi
__device__ __align__(16) unsigned short g_g1l[(size_t)N_NODES * C_HID]; // relu(agg1) lo
__device__ __align__(16) unsigned short g_h2b[(size_t)N_NODES * C_OUT]; // h2 bf16
__device__ float g_alps1[N_NODES], g_alpd1[N_NODES];
__device__ float g_alps2[N_NODES], g_alpd2[N_NODES];
__device__ int   g_deg[N_NODES];
__device__ int   g_rowstart[N_NODES + 1];
__device__ int   g_cursor[N_NODES];
__device__ int   g_srcidx[E_TOT];
__device__ int   g_bsum[40];
__device__ int   g_is64;    // edge_index arrived as raw int64 words
__device__ int   g_isf32;   // float inputs arrived as raw fp32 words

__device__ __forceinline__ float bf2f(unsigned short b){
  unsigned int u = ((unsigned int)b) << 16;
  return __builtin_bit_cast(float, u);
}
__device__ __forceinline__ unsigned short f2bf(float f){
  unsigned int u = __builtin_bit_cast(unsigned int, f);
  u += 0x7fffu + ((u >> 16) & 1u);   // round-to-nearest-even
  return (unsigned short)(u >> 16);
}
__device__ __forceinline__ int clampi(int v){
  v = v < 0 ? 0 : v;
  return v >= N_NODES ? N_NODES - 1 : v;
}
__device__ __forceinline__ void edge_sd(const int* ei, int e, int& s, int& d){
  if (e < N_EDGES){
    if (g_is64){ s = ei[2 * e]; d = ei[2 * (N_EDGES + e)]; }
    else       { s = ei[e];     d = ei[N_EDGES + e]; }
    s = clampi(s); d = clampi(d);
  } else {
    s = d = e - N_EDGES;  // self-loop
  }
}
__device__ __forceinline__ float ldw(const void* p, int i){
  return g_isf32 ? ((const float*)p)[i] : bf2f(((const unsigned short*)p)[i]);
}

struct Ptrs { const void* p[8]; };

// pack (k, n) of a [K][Nc] weight into MFMA B-fragment order
__device__ __forceinline__ int wpack(int k, int n, int Nc){
  return (((k >> 5) * (Nc / 16) + (n >> 4)) * 64 + (((k >> 3) & 3) * 16 + (n & 15))) * 8 + (k & 7);
}

// =======================================================================
// Cooperative preprocessing: probe + zero + count + scan + scatter + Wpack
// grid = 668 x 512 (342016 threads >= E_TOT); edge (s,d) kept in registers
// across grid.sync() so the edge list is decoded exactly once.
// =======================================================================
__global__ __launch_bounds__(512) void prep_k(const unsigned int* __restrict__ xw,
                                              const int* __restrict__ ei, Ptrs ps){
  cg::grid_group grid = cg::this_grid();
  __shared__ int sm[512];
  __shared__ int s_off;
  int t = (int)threadIdx.x;
  int b = (int)blockIdx.x;
  int tid = b * 512 + t;

  // ---- phase 0: zero accumulators + wave-parallel dtype/layout probes ----
  if (tid < N_NODES){
    g_deg[tid] = 0;
    g_alps1[tid] = 0.f; g_alpd1[tid] = 0.f;
    g_alps2[tid] = 0.f; g_alpd2[tid] = 0.f;
  }
  if (b == 0 && t < 64){
    int lane = t, cnt = 0;
    for (int j = lane; j < 256; j += 64){
      unsigned int e = (xw[j] >> 7) & 0xFFu;
      if (e >= 0x60u && e <= 0x8Fu) ++cnt;
    }
#pragma unroll
    for (int o = 32; o > 0; o >>= 1) cnt += __shfl_xor(cnt, o, 64);
    unsigned long long anybad = __ballot(ei[2 * lane + 1] != 0);
    if (lane == 0){
      g_isf32 = (cnt < 200) ? 1 : 0;  // bf16 ~256 in-window; fp32 ~48
      g_is64  = (anybad == 0ULL) ? 1 : 0;
    }
  }
  grid.sync();

  // ---- phase 1: decode edge once (regs), count degree; fold in W pack ----
  int es = 0, ed = 0;
  if (tid < E_TOT){
    edge_sd(ei, tid, es, ed);
    atomicAdd(&g_deg[ed], 1);
  }
  if (tid < C_IN * C_HID){
    float f = ldw(ps.p[0], tid);
    int k = tid / C_HID, n = tid % C_HID;
    int idx = wpack(k, n, C_HID);
    unsigned short h = f2bf(f);
    c_W1h[idx] = h; c_W1l[idx] = f2bf(f - bf2f(h));
  } else if (tid < C_IN * C_HID + C_HID * C_OUT){
    int j = tid - C_IN * C_HID;
    float f = ldw(ps.p[4], j);
    int k = j / C_OUT, n = j % C_OUT;
    int idx = wpack(k, n, C_OUT);
    unsigned short h = f2bf(f);
    c_W2h[idx] = h; c_W2l[idx] = f2bf(f - bf2f(h));
  } else {
    int j = tid - (C_IN * C_HID + C_HID * C_OUT);
    if      (j <  256) c_as1f[j]        = ldw(ps.p[1], j);
    else if (j <  512) c_ad1f[j - 256]  = ldw(ps.p[2], j - 256);
    else if (j <  768) c_b1f [j - 512]  = ldw(ps.p[3], j - 512);
    else if (j <  896) c_as2f[j - 768]  = ldw(ps.p[5], j - 768);
    else if (j < 1024) c_ad2f[j - 896]  = ldw(ps.p[6], j - 896);
    else if (j < 1152) c_b2f [j - 1024] = ldw(ps.p[7], j - 1024);
  }
  grid.sync();

  // ---- phase 2a: block-local exclusive scans (blocks 0..39, 500 nodes) ----
  if (b < 40){
    int i = b * 500 + t;
    int v = (t < 500) ? g_deg[i] : 0;
    sm[t] = v;
    __syncthreads();
    for (int off = 1; off < 512; off <<= 1){
      int x2 = (t >= off) ? sm[t - off] : 0;
      __syncthreads();
      sm[t] += x2;
      __syncthreads();
    }
    if (t < 500) g_rowstart[i] = sm[t] - v;
    if (t == 511) g_bsum[b] = sm[511];
  }
  grid.sync();

  // ---- phase 2b: add inter-block carries ----
  if (b < 40){
    if (t == 0){
      int o = 0;
      for (int j = 0; j < b; ++j) o += g_bsum[j];
      s_off = o;
    }
    __syncthreads();
    int i = b * 500 + t;
    if (t < 500){
      int val = g_rowstart[i] + s_off;
      g_rowstart[i] = val;
      g_cursor[i]   = val;
    }
  }
  if (b == 0 && t == 0) g_rowstart[N_NODES] = E_TOT;
  grid.sync();

  // ---- phase 3: scatter (reuses registers es, ed) ----
  if (tid < E_TOT){
    int pos = atomicAdd(&g_cursor[ed], 1);
    g_srcidx[pos] = es;
  }
}

// ---------------- split-bf16 MFMA GEMM + fused alpha epilogue ----------------
// One block = 32 rows x ALL cols. 4 waves split cols; A-frags reused from
// registers across n-tiles; W packed frag-major (coalesced).
// SEL=0 reads raw x (fp32 or bf16, split on the fly); SEL=1 reads split g1.
template<int SEL>
__global__ __launch_bounds__(256) void gemm_k(const void* __restrict__ xsrc){
  const int Nc = SEL ? C_OUT : C_HID;
  const int NT = SEL ? 2 : 4;
  const unsigned short* Wh = SEL ? c_W2h : c_W1h;
  const unsigned short* Wl = SEL ? c_W2l : c_W1l;
  unsigned short* Hb = SEL ? g_h2b : g_h1b;
  float* alps = SEL ? g_alps2 : g_alps1;
  float* alpd = SEL ? g_alpd2 : g_alpd1;
  const float* aS = SEL ? c_as2f : c_as1f;
  const float* aD = SEL ? c_ad2f : c_ad1f;
  const bool isf32 = (SEL == 0) && (g_isf32 != 0);

  int wave = (int)(threadIdx.x >> 6);
  int lane = (int)(threadIdx.x & 63);
  int kgrp = lane >> 4, cl = lane & 15;
  int mbase = blockIdx.x * 32;

  f32x4 acc[2][4];
#pragma unroll
  for (int m = 0; m < 2; ++m)
#pragma unroll
    for (int n = 0; n < NT; ++n) acc[m][n] = (f32x4){0.f, 0.f, 0.f, 0.f};

  for (int kt = 0; kt < 8; ++kt){
    int kbase = kt * 32 + kgrp * 8;
    bf16x8 ah[2], al[2];
    if (SEL == 1){
#pragma unroll
      for (int m = 0; m < 2; ++m){
        size_t ai = (size_t)(mbase + m * 16 + cl) * 256 + kbase;
        ah[m] = *(const bf16x8*)(g_g1h + ai);
        al[m] = *(const bf16x8*)(g_g1l + ai);
      }
    } else if (isf32){
      const float* Xf = (const float*)xsrc;
#pragma unroll
      for (int m = 0; m < 2; ++m){
        const float4* xp = (const float4*)(Xf + (size_t)(mbase + m * 16 + cl) * 256 + kbase);
        float4 v0 = xp[0], v1 = xp[1];
        float vals[8] = {v0.x, v0.y, v0.z, v0.w, v1.x, v1.y, v1.z, v1.w};
#pragma unroll
        for (int j = 0; j < 8; ++j){
          unsigned short h = f2bf(vals[j]);
          ah[m][j] = (short)h;
          al[m][j] = (short)f2bf(vals[j] - bf2f(h));
        }
      }
    } else {  // bf16 input: lo part is zero
      const unsigned short* Xb = (const unsigned short*)xsrc;
#pragma unroll
      for (int m = 0; m < 2; ++m){
        ah[m] = *(const bf16x8*)(Xb + (size_t)(mbase + m * 16 + cl) * 256 + kbase);
        al[m] = (bf16x8){0,0,0,0,0,0,0,0};
      }
    }
#pragma unroll
    for (int nn = 0; nn < NT; ++nn){
      int nt = wave * NT + nn;
      size_t wi = ((size_t)(kt * (Nc / 16) + nt) * 64 + lane) * 8;
      bf16x8 bh = *(const bf16x8*)(Wh + wi);
      bf16x8 bl = *(const bf16x8*)(Wl + wi);
#pragma unroll
      for (int m = 0; m < 2; ++m){
        acc[m][nn] = __builtin_amdgcn_mfma_f32_16x16x32_bf16(ah[m], bh, acc[m][nn], 0, 0, 0);
        acc[m][nn] = __builtin_amdgcn_mfma_f32_16x16x32_bf16(ah[m], bl, acc[m][nn], 0, 0, 0);
        acc[m][nn] = __builtin_amdgcn_mfma_f32_16x16x32_bf16(al[m], bh, acc[m][nn], 0, 0, 0);
      }
    }
  }

  float asv[4], adv[4];
#pragma unroll
  for (int nn = 0; nn < NT; ++nn){
    int col = (wave * NT + nn) * 16 + cl;
    asv[nn] = aS[col]; adv[nn] = aD[col];
  }
#pragma unroll
  for (int m = 0; m < 2; ++m){
#pragma unroll
    for (int i = 0; i < 4; ++i){
      int row = mbase + m * 16 + kgrp * 4 + i;
      float ps = 0.f, pd = 0.f;
#pragma unroll
      for (int nn = 0; nn < NT; ++nn){
        int col = (wave * NT + nn) * 16 + cl;
        float v = acc[m][nn][i];
        Hb[(size_t)row * Nc + col] = f2bf(v);
        ps += v * asv[nn]; pd += v * adv[nn];
      }
      ps += __shfl_xor(ps, 1);  pd += __shfl_xor(pd, 1);
      ps += __shfl_xor(ps, 2);  pd += __shfl_xor(pd, 2);
      ps += __shfl_xor(ps, 4);  pd += __shfl_xor(pd, 4);
      ps += __shfl_xor(ps, 8);  pd += __shfl_xor(pd, 8);
      if (cl == 0){
        atomicAdd(&alps[row], ps);
        atomicAdd(&alpd[row], pd);
      }
    }
  }
}

// ---------------- fused softmax + aggregation: one wave per node ----------------
#define ACC4(p, w) { \
  a0 += (w) * bf2f((unsigned short)((p).x & 0xFFFFu)); \
  a1 += (w) * bf2f((unsigned short)((p).x >> 16)); \
  a2 += (w) * bf2f((unsigned short)((p).y & 0xFFFFu)); \
  a3 += (w) * bf2f((unsigned short)((p).y >> 16)); }

#define ACC2(p, w) { \
  a0 += (w) * bf2f((unsigned short)((p) & 0xFFFFu)); \
  a1 += (w) * bf2f((unsigned short)((p) >> 16)); }

template<int F, int SEL>
__global__ void agg_k(float* OUT){
  const unsigned short* Hb = SEL ? g_h2b : g_h1b;
  const float* bias = SEL ? c_b2f : c_b1f;
  const float* alps = SEL ? g_alps2 : g_alps1;
  const float* alpd = SEL ? g_alpd2 : g_alpd1;
  int lane = threadIdx.x & 63;
  int n = blockIdx.x * 4 + (threadIdx.x >> 6);
  int i0 = g_rowstart[n], i1 = g_rowstart[n + 1];
  float adn = alpd[n];
  float dpart = 0.f;
  float a0 = 0.f, a1 = 0.f, a2 = 0.f, a3 = 0.f;
  const uint2* H2 = (const uint2*)Hb;
  const unsigned int* H1 = (const unsigned int*)Hb;

  for (int base = i0; base < i1; base += 64){
    int nv = i1 - base; if (nv > 64) nv = 64;
    int sv = 0; float wv = 0.f;
    if (lane < nv){
      sv = g_srcidx[base + lane];
      float e = alps[sv] + adn;
      e = (e > 0.f) ? e : NEG_SLOPE * e;
      wv = __expf(e);
    }
    dpart += wv;
    int j = 0;
    for (; j + 4 <= nv; j += 4){
      int s0 = __shfl(sv, j),     s1 = __shfl(sv, j + 1);
      int s2 = __shfl(sv, j + 2), s3 = __shfl(sv, j + 3);
      float w0 = __shfl(wv, j),     w1 = __shfl(wv, j + 1);
      float w2 = __shfl(wv, j + 2), w3 = __shfl(wv, j + 3);
      if constexpr (F == 256){
        uint2 p0 = H2[(size_t)s0 * 64 + lane];
        uint2 p1 = H2[(size_t)s1 * 64 + lane];
        uint2 p2 = H2[(size_t)s2 * 64 + lane];
        uint2 p3 = H2[(size_t)s3 * 64 + lane];
        ACC4(p0, w0) ACC4(p1, w1) ACC4(p2, w2) ACC4(p3, w3)
      } else {
        unsigned int p0 = H1[(size_t)s0 * 64 + lane];
        unsigned int p1 = H1[(size_t)s1 * 64 + lane];
        unsigned int p2 = H1[(size_t)s2 * 64 + lane];
        unsigned int p3 = H1[(size_t)s3 * 64 + lane];
        ACC2(p0, w0) ACC2(p1, w1) ACC2(p2, w2) ACC2(p3, w3)
      }
    }
    for (; j < nv; ++j){
      int s = __shfl(sv, j);
      float w = __shfl(wv, j);
      if constexpr (F == 256){
        uint2 p = H2[(size_t)s * 64 + lane];
        ACC4(p, w)
      } else {
        unsigned int p = H1[(size_t)s * 64 + lane];
        ACC2(p, w)
      }
    }
  }

  float den = dpart;
#pragma unroll
  for (int o = 32; o > 0; o >>= 1) den += __shfl_xor(den, o, 64);
  float inv = 1.f / den;

  if constexpr (F == 256){
    float o0 = a0 * inv + bias[4 * lane];
    float o1 = a1 * inv + bias[4 * lane + 1];
    float o2 = a2 * inv + bias[4 * lane + 2];
    float o3 = a3 * inv + bias[4 * lane + 3];
    if (SEL == 0){
      o0 = fmaxf(o0, 0.f); o1 = fmaxf(o1, 0.f);
      o2 = fmaxf(o2, 0.f); o3 = fmaxf(o3, 0.f);
      unsigned short h0 = f2bf(o0), h1 = f2bf(o1), h2 = f2bf(o2), h3 = f2bf(o3);
      uint2 ph, pl;
      ph.x = (unsigned)h0 | ((unsigned)h1 << 16);
      ph.y = (unsigned)h2 | ((unsigned)h3 << 16);
      pl.x = (unsigned)f2bf(o0 - bf2f(h0)) | ((unsigned)f2bf(o1 - bf2f(h1)) << 16);
      pl.y = (unsigned)f2bf(o2 - bf2f(h2)) | ((unsigned)f2bf(o3 - bf2f(h3)) << 16);
      ((uint2*)g_g1h)[(size_t)n * 64 + lane] = ph;
      ((uint2*)g_g1l)[(size_t)n * 64 + lane] = pl;
    } else {
      float4 o; o.x = o0; o.y = o1; o.z = o2; o.w = o3;
      ((float4*)OUT)[(size_t)n * 64 + lane] = o;
    }
  } else {
    float o0 = a0 * inv + bias[2 * lane];
    float o1 = a1 * inv + bias[2 * lane + 1];
    if (SEL == 0){
      o0 = fmaxf(o0, 0.f); o1 = fmaxf(o1, 0.f);
      unsigned short h0 = f2bf(o0), h1 = f2bf(o1);
      ((unsigned int*)g_g1h)[(size_t)n * 64 + lane] = (unsigned)h0 | ((unsigned)h1 << 16);
      ((unsigned int*)g_g1l)[(size_t)n * 64 + lane] =
        (unsigned)f2bf(o0 - bf2f(h0)) | ((unsigned)f2bf(o1 - bf2f(h1)) << 16);
    } else {
      float2 o; o.x = o0; o.y = o1;
      ((float2*)OUT)[(size_t)n * 64 + lane] = o;
    }
  }
}

extern "C" void kernel_launch(void* const* d_in, const int* in_sizes, int n_in,
                              void* d_out, int out_size, void* d_ws, size_t ws_size,
                              hipStream_t stream){
  (void)in_sizes; (void)n_in; (void)out_size; (void)d_ws; (void)ws_size;
  const void* x  = d_in[0];
  const int*  ei = (const int*)d_in[1];
  float* out = (float*)d_out;

  Ptrs ps;
  ps.p[0] = d_in[2]; ps.p[1] = d_in[3]; ps.p[2] = d_in[4]; ps.p[3] = d_in[5];
  ps.p[4] = d_in[6]; ps.p[5] = d_in[7]; ps.p[6] = d_in[8]; ps.p[7] = d_in[9];

  // cooperative preprocessing: probe+zero+Wpack+count+scan+scatter in ONE kernel
  const unsigned int* xw = (const unsigned int*)x;
  void* args[3] = { (void*)&xw, (void*)&ei, (void*)&ps };
  hipLaunchCooperativeKernel(reinterpret_cast<void*>(prep_k),
                             dim3(668), dim3(512), args, 0, stream);

  // ---- layer 1 ----
  gemm_k<0><<<N_NODES / 32, 256, 0, stream>>>(x);
  agg_k<C_HID, 0><<<N_NODES / 4, 256, 0, stream>>>(nullptr);

  // ---- layer 2 ----
  gemm_k<1><<<N_NODES / 32, 256, 0, stream>>>(nullptr);
  agg_k<C_OUT, 1><<<N_NODES / 4, 256, 0, stream>>>(out);
}

// Round 12
// 215.315 us; speedup vs baseline: 2.3685x; 2.3685x over previous
//
#include <hip/hip_runtime.h>
#include <math.h>

#define N_NODES 20000
#define N_EDGES 320000
#define E_TOT   (N_EDGES + N_NODES)
#define C_IN  256
#define C_HID 256
#define C_OUT 128
#define NEG_SLOPE 0.2f

typedef __attribute__((ext_vector_type(8))) short bf16x8;
typedef __attribute__((ext_vector_type(4))) float f32x4;

// ---- all scratch in module globals (ws_size unknown; globals are safe) ----
// weights packed in MFMA-fragment order: idx = ((kt*(Nc/16)+ntile)*64 + kgrp*16+col%16)*8 + k%8
__device__ __align__(16) unsigned short c_W1h[C_IN * C_HID], c_W1l[C_IN * C_HID];
__device__ __align__(16) unsigned short c_W2h[C_HID * C_OUT], c_W2l[C_HID * C_OUT];
__device__ float c_as1f[C_HID], c_ad1f[C_HID], c_b1f[C_HID];
__device__ float c_as2f[C_OUT], c_ad2f[C_OUT], c_b2f[C_OUT];
__device__ __align__(16) unsigned short g_h1b[(size_t)N_NODES * C_HID]; // h1 bf16
__device__ __align__(16) unsigned short g_g1h[(size_t)N_NODES * C_HID]; // relu(agg1) hi
__device__ __align__(16) unsigned short g_g1l[(size_t)N_NODES * C_HID]; // relu(agg1) lo
__device__ __align__(16) unsigned short g_h2b[(size_t)N_NODES * C_OUT]; // h2 bf16
__device__ float g_alps1[N_NODES], g_alpd1[N_NODES];
__device__ float g_alps2[N_NODES], g_alpd2[N_NODES];
__device__ int   g_deg[N_NODES];
__device__ int   g_rowstart[N_NODES + 1];
__device__ int   g_cursor[N_NODES];
__device__ int   g_srcidx[E_TOT];
__device__ int   g_bsum[20];
__device__ int   g_is64;    // edge_index arrived as raw int64 words
__device__ int   g_isf32;   // float inputs arrived as raw fp32 words

__device__ __forceinline__ float bf2f(unsigned short b){
  unsigned int u = ((unsigned int)b) << 16;
  return __builtin_bit_cast(float, u);
}
__device__ __forceinline__ unsigned short f2bf(float f){
  unsigned int u = __builtin_bit_cast(unsigned int, f);
  u += 0x7fffu + ((u >> 16) & 1u);   // round-to-nearest-even
  return (unsigned short)(u >> 16);
}
__device__ __forceinline__ int clampi(int v){
  v = v < 0 ? 0 : v;
  return v >= N_NODES ? N_NODES - 1 : v;
}
__device__ __forceinline__ void edge_sd(const int* ei, int e, int& s, int& d){
  if (e < N_EDGES){
    if (g_is64){ s = ei[2 * e]; d = ei[2 * (N_EDGES + e)]; }
    else       { s = ei[e];     d = ei[N_EDGES + e]; }
    s = clampi(s); d = clampi(d);
  } else {
    s = d = e - N_EDGES;  // self-loop
  }
}

// ---------------- probes + zero init (fused) ----------------
// NOTE (R9 lesson): cooperative grid.sync() costs ~80us each on gfx950
// (8 non-coherent XCDs) - separate small dispatches are far cheaper.
// Probe is wave-parallel (proven in R9): serial thread-0 probe hides
// ~320 dependent cold loads (~15-25us).
__global__ void probe_zero_k(const unsigned int* __restrict__ xw, const int* __restrict__ ei){
  int i = blockIdx.x * blockDim.x + threadIdx.x;
  if (i < N_NODES){
    g_deg[i] = 0;
    g_alps1[i] = 0.f; g_alpd1[i] = 0.f;
    g_alps2[i] = 0.f; g_alpd2[i] = 0.f;
  }
  if (blockIdx.x == 0 && threadIdx.x < 64){
    int lane = (int)threadIdx.x, cnt = 0;
    for (int j = lane; j < 256; j += 64){
      unsigned int e = (xw[j] >> 7) & 0xFFu;
      if (e >= 0x60u && e <= 0x8Fu) ++cnt;
    }
#pragma unroll
    for (int o = 32; o > 0; o >>= 1) cnt += __shfl_xor(cnt, o, 64);
    unsigned long long anybad = __ballot(ei[2 * lane + 1] != 0);
    if (lane == 0){
      g_isf32 = (cnt < 200) ? 1 : 0;  // bf16 ~256 in-window; fp32 ~48
      g_is64  = (anybad == 0ULL) ? 1 : 0;
    }
  }
}

struct Ptrs { const void* p[8]; };

// pack (k, n) of a [K][Nc] weight into MFMA B-fragment order
__device__ __forceinline__ int wpack(int k, int n, int Nc){
  return (((k >> 5) * (Nc / 16) + (n >> 4)) * 64 + (((k >> 3) & 3) * 16 + (n & 15))) * 8 + (k & 7);
}

__global__ void cvt_w_k(Ptrs ps){
  // b: 0=W1 1=a_src1 2=a_dst1 3=b1 4=W2 5=a_src2 6=a_dst2 7=b2
  const int sizes[8] = {C_IN * C_HID, C_HID, C_HID, C_HID,
                        C_HID * C_OUT, C_OUT, C_OUT, C_OUT};
  int b = blockIdx.y;
  int i = blockIdx.x * blockDim.x + threadIdx.x;
  if (i >= sizes[b]) return;
  const void* s = ps.p[b];
  float f = g_isf32 ? ((const float*)s)[i] : bf2f(((const unsigned short*)s)[i]);
  if (b == 0){                           // W1[k][n]
    int k = i / C_HID, n = i % C_HID;
    int idx = wpack(k, n, C_HID);
    unsigned short h = f2bf(f);
    c_W1h[idx] = h; c_W1l[idx] = f2bf(f - bf2f(h));
  } else if (b == 4){                    // W2[k][n]
    int k = i / C_OUT, n = i % C_OUT;
    int idx = wpack(k, n, C_OUT);
    unsigned short h = f2bf(f);
    c_W2h[idx] = h; c_W2l[idx] = f2bf(f - bf2f(h));
  } else {
    float* vd = (b == 1) ? c_as1f : (b == 2) ? c_ad1f : (b == 3) ? c_b1f
              : (b == 5) ? c_as2f : (b == 6) ? c_ad2f : c_b2f;
    vd[i] = f;
  }
}

// ---------------- graph preprocessing ----------------
__global__ void count_k(const int* __restrict__ ei){
  int e = blockIdx.x * blockDim.x + threadIdx.x;
  if (e >= E_TOT) return;
  int s, d;
  edge_sd(ei, e, s, d);
  atomicAdd(&g_deg[d], 1);
}

// two-phase multi-block exclusive scan of deg[20000]: 20 blocks x 1000
__global__ void scanA_k(){
  __shared__ int s[1024];
  int b = blockIdx.x, t = threadIdx.x;
  int i = b * 1000 + t;
  int v = (t < 1000) ? g_deg[i] : 0;
  s[t] = v;
  __syncthreads();
  for (int off = 1; off < 1024; off <<= 1){
    int x = (t >= off) ? s[t - off] : 0;
    __syncthreads();
    s[t] += x;
    __syncthreads();
  }
  if (t < 1000) g_rowstart[i] = s[t] - v;   // block-local exclusive
  if (t == 1023) g_bsum[b] = s[1023];
}

__global__ void scanC_k(){
  __shared__ int off;
  int b = blockIdx.x, t = threadIdx.x;
  if (t == 0){
    int o = 0;
    for (int j = 0; j < b; ++j) o += g_bsum[j];
    off = o;
  }
  __syncthreads();
  int i = b * 1000 + t;
  if (t < 1000){
    int val = g_rowstart[i] + off;
    g_rowstart[i] = val;
    g_cursor[i]   = val;
  }
  if (b == 0 && t == 0) g_rowstart[N_NODES] = E_TOT;
}

__global__ void scatter_k(const int* __restrict__ ei){
  int e = blockIdx.x * blockDim.x + threadIdx.x;
  if (e >= E_TOT) return;
  int s, d;
  edge_sd(ei, e, s, d);
  int pos = atomicAdd(&g_cursor[d], 1);
  g_srcidx[pos] = s;
}

// ---------------- split-bf16 MFMA GEMM + fused alpha epilogue ----------------
// One block = 32 rows x ALL cols. 4 waves split cols; A-frags reused from
// registers across n-tiles; W packed frag-major (coalesced).
// SEL=0 reads raw x (fp32 or bf16, split on the fly); SEL=1 reads split g1.
template<int SEL>
__global__ __launch_bounds__(256) void gemm_k(const void* __restrict__ xsrc){
  const int Nc = SEL ? C_OUT : C_HID;
  const int NT = SEL ? 2 : 4;
  const unsigned short* Wh = SEL ? c_W2h : c_W1h;
  const unsigned short* Wl = SEL ? c_W2l : c_W1l;
  unsigned short* Hb = SEL ? g_h2b : g_h1b;
  float* alps = SEL ? g_alps2 : g_alps1;
  float* alpd = SEL ? g_alpd2 : g_alpd1;
  const float* aS = SEL ? c_as2f : c_as1f;
  const float* aD = SEL ? c_ad2f : c_ad1f;
  const bool isf32 = (SEL == 0) && (g_isf32 != 0);

  int wave = (int)(threadIdx.x >> 6);
  int lane = (int)(threadIdx.x & 63);
  int kgrp = lane >> 4, cl = lane & 15;
  int mbase = blockIdx.x * 32;

  f32x4 acc[2][4];
#pragma unroll
  for (int m = 0; m < 2; ++m)
#pragma unroll
    for (int n = 0; n < NT; ++n) acc[m][n] = (f32x4){0.f, 0.f, 0.f, 0.f};

  for (int kt = 0; kt < 8; ++kt){
    int kbase = kt * 32 + kgrp * 8;
    bf16x8 ah[2], al[2];
    if (SEL == 1){
#pragma unroll
      for (int m = 0; m < 2; ++m){
        size_t ai = (size_t)(mbase + m * 16 + cl) * 256 + kbase;
        ah[m] = *(const bf16x8*)(g_g1h + ai);
        al[m] = *(const bf16x8*)(g_g1l + ai);
      }
    } else if (isf32){
      const float* Xf = (const float*)xsrc;
#pragma unroll
      for (int m = 0; m < 2; ++m){
        const float4* xp = (const float4*)(Xf + (size_t)(mbase + m * 16 + cl) * 256 + kbase);
        float4 v0 = xp[0], v1 = xp[1];
        float vals[8] = {v0.x, v0.y, v0.z, v0.w, v1.x, v1.y, v1.z, v1.w};
#pragma unroll
        for (int j = 0; j < 8; ++j){
          unsigned short h = f2bf(vals[j]);
          ah[m][j] = (short)h;
          al[m][j] = (short)f2bf(vals[j] - bf2f(h));
        }
      }
    } else {  // bf16 input: lo part is zero
      const unsigned short* Xb = (const unsigned short*)xsrc;
#pragma unroll
      for (int m = 0; m < 2; ++m){
        ah[m] = *(const bf16x8*)(Xb + (size_t)(mbase + m * 16 + cl) * 256 + kbase);
        al[m] = (bf16x8){0,0,0,0,0,0,0,0};
      }
    }
#pragma unroll
    for (int nn = 0; nn < NT; ++nn){
      int nt = wave * NT + nn;
      size_t wi = ((size_t)(kt * (Nc / 16) + nt) * 64 + lane) * 8;
      bf16x8 bh = *(const bf16x8*)(Wh + wi);
      bf16x8 bl = *(const bf16x8*)(Wl + wi);
#pragma unroll
      for (int m = 0; m < 2; ++m){
        acc[m][nn] = __builtin_amdgcn_mfma_f32_16x16x32_bf16(ah[m], bh, acc[m][nn], 0, 0, 0);
        acc[m][nn] = __builtin_amdgcn_mfma_f32_16x16x32_bf16(ah[m], bl, acc[m][nn], 0, 0, 0);
        acc[m][nn] = __builtin_amdgcn_mfma_f32_16x16x32_bf16(al[m], bh, acc[m][nn], 0, 0, 0);
      }
    }
  }

  float asv[4], adv[4];
#pragma unroll
  for (int nn = 0; nn < NT; ++nn){
    int col = (wave * NT + nn) * 16 + cl;
    asv[nn] = aS[col]; adv[nn] = aD[col];
  }
#pragma unroll
  for (int m = 0; m < 2; ++m){
#pragma unroll
    for (int i = 0; i < 4; ++i){
      int row = mbase + m * 16 + kgrp * 4 + i;
      float ps = 0.f, pd = 0.f;
#pragma unroll
      for (int nn = 0; nn < NT; ++nn){
        int col = (wave * NT + nn) * 16 + cl;
        float v = acc[m][nn][i];
        Hb[(size_t)row * Nc + col] = f2bf(v);
        ps += v * asv[nn]; pd += v * adv[nn];
      }
      ps += __shfl_xor(ps, 1);  pd += __shfl_xor(pd, 1);
      ps += __shfl_xor(ps, 2);  pd += __shfl_xor(pd, 2);
      ps += __shfl_xor(ps, 4);  pd += __shfl_xor(pd, 4);
      ps += __shfl_xor(ps, 8);  pd += __shfl_xor(pd, 8);
      if (cl == 0){
        atomicAdd(&alps[row], ps);
        atomicAdd(&alpd[row], pd);
      }
    }
  }
}

// ---------------- fused softmax + aggregation: one wave per node ----------------
// R8-proven structure (chunk 64 edges: lane j computes exp once, shfl
// broadcast, uniform full-wave gather per edge), widened to 8 loads in
// flight per unrolled iteration.
#define ACC4(p, ww) { \
  a0 += (ww) * bf2f((unsigned short)((p).x & 0xFFFFu)); \
  a1 += (ww) * bf2f((unsigned short)((p).x >> 16)); \
  a2 += (ww) * bf2f((unsigned short)((p).y & 0xFFFFu)); \
  a3 += (ww) * bf2f((unsigned short)((p).y >> 16)); }

#define ACC2(p, ww) { \
  a0 += (ww) * bf2f((unsigned short)((p) & 0xFFFFu)); \
  a1 += (ww) * bf2f((unsigned short)((p) >> 16)); }

template<int F, int SEL>
__global__ void agg_k(float* OUT){
  const unsigned short* Hb = SEL ? g_h2b : g_h1b;
  const float* bias = SEL ? c_b2f : c_b1f;
  const float* alps = SEL ? g_alps2 : g_alps1;
  const float* alpd = SEL ? g_alpd2 : g_alpd1;
  int lane = threadIdx.x & 63;
  int n = blockIdx.x * 4 + (threadIdx.x >> 6);
  int i0 = g_rowstart[n], i1 = g_rowstart[n + 1];
  float adn = alpd[n];
  float dpart = 0.f;
  float a0 = 0.f, a1 = 0.f, a2 = 0.f, a3 = 0.f;
  const uint2* H2 = (const uint2*)Hb;          // F=256: lane owns 4 feats
  const unsigned int* H1 = (const unsigned int*)Hb; // F=128: lane owns 2 feats

  for (int base = i0; base < i1; base += 64){
    int nv = i1 - base; if (nv > 64) nv = 64;
    int sv = 0; float wv = 0.f;
    if (lane < nv){
      sv = g_srcidx[base + lane];
      float e = alps[sv] + adn;
      e = (e > 0.f) ? e : NEG_SLOPE * e;
      wv = __expf(e);
    }
    dpart += wv;
    int j = 0;
    for (; j + 8 <= nv; j += 8){
      int s0 = __shfl(sv, j),     s1 = __shfl(sv, j + 1);
      int s2 = __shfl(sv, j + 2), s3 = __shfl(sv, j + 3);
      int s4 = __shfl(sv, j + 4), s5 = __shfl(sv, j + 5);
      int s6 = __shfl(sv, j + 6), s7 = __shfl(sv, j + 7);
      float w0 = __shfl(wv, j),     w1 = __shfl(wv, j + 1);
      float w2 = __shfl(wv, j + 2), w3 = __shfl(wv, j + 3);
      float w4 = __shfl(wv, j + 4), w5 = __shfl(wv, j + 5);
      float w6 = __shfl(wv, j + 6), w7 = __shfl(wv, j + 7);
      if constexpr (F == 256){
        uint2 p0 = H2[(size_t)s0 * 64 + lane];
        uint2 p1 = H2[(size_t)s1 * 64 + lane];
        uint2 p2 = H2[(size_t)s2 * 64 + lane];
        uint2 p3 = H2[(size_t)s3 * 64 + lane];
        uint2 p4 = H2[(size_t)s4 * 64 + lane];
        uint2 p5 = H2[(size_t)s5 * 64 + lane];
        uint2 p6 = H2[(size_t)s6 * 64 + lane];
        uint2 p7 = H2[(size_t)s7 * 64 + lane];
        ACC4(p0, w0) ACC4(p1, w1) ACC4(p2, w2) ACC4(p3, w3)
        ACC4(p4, w4) ACC4(p5, w5) ACC4(p6, w6) ACC4(p7, w7)
      } else {
        unsigned int p0 = H1[(size_t)s0 * 64 + lane];
        unsigned int p1 = H1[(size_t)s1 * 64 + lane];
        unsigned int p2 = H1[(size_t)s2 * 64 + lane];
        unsigned int p3 = H1[(size_t)s3 * 64 + lane];
        unsigned int p4 = H1[(size_t)s4 * 64 + lane];
        unsigned int p5 = H1[(size_t)s5 * 64 + lane];
        unsigned int p6 = H1[(size_t)s6 * 64 + lane];
        unsigned int p7 = H1[(size_t)s7 * 64 + lane];
        ACC2(p0, w0) ACC2(p1, w1) ACC2(p2, w2) ACC2(p3, w3)
        ACC2(p4, w4) ACC2(p5, w5) ACC2(p6, w6) ACC2(p7, w7)
      }
    }
    for (; j + 4 <= nv; j += 4){
      int s0 = __shfl(sv, j),     s1 = __shfl(sv, j + 1);
      int s2 = __shfl(sv, j + 2), s3 = __shfl(sv, j + 3);
      float w0 = __shfl(wv, j),     w1 = __shfl(wv, j + 1);
      float w2 = __shfl(wv, j + 2), w3 = __shfl(wv, j + 3);
      if constexpr (F == 256){
        uint2 p0 = H2[(size_t)s0 * 64 + lane];
        uint2 p1 = H2[(size_t)s1 * 64 + lane];
        uint2 p2 = H2[(size_t)s2 * 64 + lane];
        uint2 p3 = H2[(size_t)s3 * 64 + lane];
        ACC4(p0, w0) ACC4(p1, w1) ACC4(p2, w2) ACC4(p3, w3)
      } else {
        unsigned int p0 = H1[(size_t)s0 * 64 + lane];
        unsigned int p1 = H1[(size_t)s1 * 64 + lane];
        unsigned int p2 = H1[(size_t)s2 * 64 + lane];
        unsigned int p3 = H1[(size_t)s3 * 64 + lane];
        ACC2(p0, w0) ACC2(p1, w1) ACC2(p2, w2) ACC2(p3, w3)
      }
    }
    for (; j < nv; ++j){
      int s = __shfl(sv, j);
      float w = __shfl(wv, j);
      if constexpr (F == 256){
        uint2 p = H2[(size_t)s * 64 + lane];
        ACC4(p, w)
      } else {
        unsigned int p = H1[(size_t)s * 64 + lane];
        ACC2(p, w)
      }
    }
  }

  float den = dpart;
#pragma unroll
  for (int o = 32; o > 0; o >>= 1) den += __shfl_xor(den, o, 64);
  float inv = 1.f / den;

  if constexpr (F == 256){
    float o0 = a0 * inv + bias[4 * lane];
    float o1 = a1 * inv + bias[4 * lane + 1];
    float o2 = a2 * inv + bias[4 * lane + 2];
    float o3 = a3 * inv + bias[4 * lane + 3];
    if (SEL == 0){
      o0 = fmaxf(o0, 0.f); o1 = fmaxf(o1, 0.f);
      o2 = fmaxf(o2, 0.f); o3 = fmaxf(o3, 0.f);
      unsigned short h0 = f2bf(o0), h1 = f2bf(o1), h2 = f2bf(o2), h3 = f2bf(o3);
      uint2 ph, pl;
      ph.x = (unsigned)h0 | ((unsigned)h1 << 16);
      ph.y = (unsigned)h2 | ((unsigned)h3 << 16);
      pl.x = (unsigned)f2bf(o0 - bf2f(h0)) | ((unsigned)f2bf(o1 - bf2f(h1)) << 16);
      pl.y = (unsigned)f2bf(o2 - bf2f(h2)) | ((unsigned)f2bf(o3 - bf2f(h3)) << 16);
      ((uint2*)g_g1h)[(size_t)n * 64 + lane] = ph;
      ((uint2*)g_g1l)[(size_t)n * 64 + lane] = pl;
    } else {
      float4 o; o.x = o0; o.y = o1; o.z = o2; o.w = o3;
      ((float4*)OUT)[(size_t)n * 64 + lane] = o;
    }
  } else {
    float o0 = a0 * inv + bias[2 * lane];
    float o1 = a1 * inv + bias[2 * lane + 1];
    if (SEL == 0){
      o0 = fmaxf(o0, 0.f); o1 = fmaxf(o1, 0.f);
      unsigned short h0 = f2bf(o0), h1 = f2bf(o1);
      ((unsigned int*)g_g1h)[(size_t)n * 64 + lane] = (unsigned)h0 | ((unsigned)h1 << 16);
      ((unsigned int*)g_g1l)[(size_t)n * 64 + lane] =
        (unsigned)f2bf(o0 - bf2f(h0)) | ((unsigned)f2bf(o1 - bf2f(h1)) << 16);
    } else {
      float2 o; o.x = o0; o.y = o1;
      ((float2*)OUT)[(size_t)n * 64 + lane] = o;
    }
  }
}

extern "C" void kernel_launch(void* const* d_in, const int* in_sizes, int n_in,
                              void* d_out, int out_size, void* d_ws, size_t ws_size,
                              hipStream_t stream){
  (void)in_sizes; (void)n_in; (void)out_size; (void)d_ws; (void)ws_size;
  const void* x  = d_in[0];
  const int*  ei = (const int*)d_in[1];
  float* out = (float*)d_out;

  probe_zero_k<<<(N_NODES + 255) / 256, 256, 0, stream>>>((const unsigned int*)x, ei);
  Ptrs ps;
  ps.p[0] = d_in[2]; ps.p[1] = d_in[3]; ps.p[2] = d_in[4]; ps.p[3] = d_in[5];
  ps.p[4] = d_in[6]; ps.p[5] = d_in[7]; ps.p[6] = d_in[8]; ps.p[7] = d_in[9];
  cvt_w_k<<<dim3((C_IN * C_HID + 255) / 256, 8), 256, 0, stream>>>(ps);

  count_k<<<(E_TOT + 255) / 256, 256, 0, stream>>>(ei);
  scanA_k<<<20, 1024, 0, stream>>>();
  scanC_k<<<20, 1024, 0, stream>>>();
  scatter_k<<<(E_TOT + 255) / 256, 256, 0, stream>>>(ei);

  // ---- layer 1 ----
  gemm_k<0><<<N_NODES / 32, 256, 0, stream>>>(x);
  agg_k<C_HID, 0><<<N_NODES / 4, 256, 0, stream>>>(nullptr);

  // ---- layer 2 ----
  gemm_k<1><<<N_NODES / 32, 256, 0, stream>>>(nullptr);
  agg_k<C_OUT, 1><<<N_NODES / 4, 256, 0, stream>>>(out);
}

// Round 13
// 192.495 us; speedup vs baseline: 2.6492x; 1.1185x over previous
//
#include <hip/hip_runtime.h>
#include <math.h>

#define N_NODES 20000
#define N_EDGES 320000
#define E_TOT   (N_EDGES + N_NODES)
#define C_IN  256
#define C_HID 256
#define C_OUT 128
#define NEG_SLOPE 0.2f
#define CAP   256   // padded-CSR slots per node; mean deg 16, sigma 4 -> >50 sigma margin

typedef __attribute__((ext_vector_type(8))) short bf16x8;
typedef __attribute__((ext_vector_type(4))) float f32x4;

// ---- all scratch in module globals (ws_size unknown; globals are safe) ----
// weights packed in MFMA-fragment order: idx = ((kt*(Nc/16)+ntile)*64 + kgrp*16+col%16)*8 + k%8
__device__ __align__(16) unsigned short c_W1h[C_IN * C_HID], c_W1l[C_IN * C_HID];
__device__ __align__(16) unsigned short c_W2h[C_HID * C_OUT], c_W2l[C_HID * C_OUT];
__device__ float c_as1f[C_HID], c_ad1f[C_HID], c_b1f[C_HID];
__device__ float c_as2f[C_OUT], c_ad2f[C_OUT], c_b2f[C_OUT];
__device__ __align__(16) unsigned short g_h1b[(size_t)N_NODES * C_HID]; // h1 bf16
__device__ __align__(16) unsigned short g_g1h[(size_t)N_NODES * C_HID]; // relu(agg1) hi
__device__ __align__(16) unsigned short g_g1l[(size_t)N_NODES * C_HID]; // relu(agg1) lo
__device__ __align__(16) unsigned short g_h2b[(size_t)N_NODES * C_OUT]; // h2 bf16
__device__ float g_alps1[N_NODES], g_alpd1[N_NODES];
__device__ float g_alps2[N_NODES], g_alpd2[N_NODES];
__device__ int   g_cursor[N_NODES];            // doubles as per-node edge count
__device__ int   g_srcidx[(size_t)N_NODES * CAP];
__device__ int   g_is64;    // edge_index arrived as raw int64 words
__device__ int   g_isf32;   // float inputs arrived as raw fp32 words

__device__ __forceinline__ float bf2f(unsigned short b){
  unsigned int u = ((unsigned int)b) << 16;
  return __builtin_bit_cast(float, u);
}
__device__ __forceinline__ unsigned short f2bf(float f){
  unsigned int u = __builtin_bit_cast(unsigned int, f);
  u += 0x7fffu + ((u >> 16) & 1u);   // round-to-nearest-even
  return (unsigned short)(u >> 16);
}
__device__ __forceinline__ int clampi(int v){
  v = v < 0 ? 0 : v;
  return v >= N_NODES ? N_NODES - 1 : v;
}
__device__ __forceinline__ void edge_sd(const int* ei, int e, int& s, int& d){
  if (e < N_EDGES){
    if (g_is64){ s = ei[2 * e]; d = ei[2 * (N_EDGES + e)]; }
    else       { s = ei[e];     d = ei[N_EDGES + e]; }
    s = clampi(s); d = clampi(d);
  } else {
    s = d = e - N_EDGES;  // self-loop
  }
}

struct Ptrs { const void* p[8]; };

// pack (k, n) of a [K][Nc] weight into MFMA B-fragment order
__device__ __forceinline__ int wpack(int k, int n, int Nc){
  return (((k >> 5) * (Nc / 16) + (n >> 4)) * 64 + (((k >> 3) & 3) * 16 + (n & 15))) * 8 + (k & 7);
}

// =======================================================================
// prep_k: probe publish + zero accumulators + weight pack, ONE dispatch.
// Each block derives isf32 inline from 1 KB of x (L2 broadcast) so there
// is no cross-block ordering requirement within the kernel.
// threads: [0,20000) zero | [20000,85536) W1 | [85536,118304) W2 | +1152 vecs
// =======================================================================
#define PREP_Z  N_NODES
#define PREP_W1 (C_IN * C_HID)
#define PREP_W2 (C_HID * C_OUT)
#define PREP_T  (PREP_Z + PREP_W1 + PREP_W2 + 2 * C_HID + C_HID + 2 * C_OUT + C_OUT)

__global__ void prep_k(const unsigned int* __restrict__ xw,
                       const int* __restrict__ ei, Ptrs ps){
  __shared__ int s_isf32;
  if (threadIdx.x < 64){
    int lane = (int)threadIdx.x, cnt = 0;
    for (int j = lane; j < 256; j += 64){
      unsigned int e = (xw[j] >> 7) & 0xFFu;
      if (e >= 0x60u && e <= 0x8Fu) ++cnt;
    }
#pragma unroll
    for (int o = 32; o > 0; o >>= 1) cnt += __shfl_xor(cnt, o, 64);
    if (lane == 0) s_isf32 = (cnt < 200) ? 1 : 0;  // bf16 ~256 in-win; fp32 ~48
  }
  __syncthreads();
  const int isf32 = s_isf32;

  if (blockIdx.x == 0 && threadIdx.x < 64){        // publish for later dispatches
    unsigned long long anybad = __ballot(ei[2 * (int)threadIdx.x + 1] != 0);
    if (threadIdx.x == 0){ g_isf32 = isf32; g_is64 = (anybad == 0ULL) ? 1 : 0; }
  }

  int tid = (int)(blockIdx.x * blockDim.x + threadIdx.x);
  if (tid < PREP_Z){
    g_cursor[tid] = 0;
    g_alps1[tid] = 0.f; g_alpd1[tid] = 0.f;
    g_alps2[tid] = 0.f; g_alpd2[tid] = 0.f;
    return;
  }
  int j = tid - PREP_Z;
  auto ld = [&](const void* p, int i) -> float {
    return isf32 ? ((const float*)p)[i] : bf2f(((const unsigned short*)p)[i]);
  };
  if (j < PREP_W1){
    float f = ld(ps.p[0], j);
    int k = j / C_HID, n = j % C_HID;
    int idx = wpack(k, n, C_HID);
    unsigned short h = f2bf(f);
    c_W1h[idx] = h; c_W1l[idx] = f2bf(f - bf2f(h));
    return;
  }
  j -= PREP_W1;
  if (j < PREP_W2){
    float f = ld(ps.p[4], j);
    int k = j / C_OUT, n = j % C_OUT;
    int idx = wpack(k, n, C_OUT);
    unsigned short h = f2bf(f);
    c_W2h[idx] = h; c_W2l[idx] = f2bf(f - bf2f(h));
    return;
  }
  j -= PREP_W2;
  if      (j <  256) c_as1f[j]        = ld(ps.p[1], j);
  else if (j <  512) c_ad1f[j - 256]  = ld(ps.p[2], j - 256);
  else if (j <  768) c_b1f [j - 512]  = ld(ps.p[3], j - 512);
  else if (j <  896) c_as2f[j - 768]  = ld(ps.p[5], j - 768);
  else if (j < 1024) c_ad2f[j - 896]  = ld(ps.p[6], j - 896);
  else if (j < 1152) c_b2f [j - 1024] = ld(ps.p[7], j - 1024);
}

// ---------------- padded-CSR scatter: no count/scan needed ----------------
__global__ void scatter_k(const int* __restrict__ ei){
  int e = blockIdx.x * blockDim.x + threadIdx.x;
  if (e >= E_TOT) return;
  int s, d;
  edge_sd(ei, e, s, d);
  int pos = atomicAdd(&g_cursor[d], 1);
  if (pos < CAP) g_srcidx[(size_t)d * CAP + pos] = s;  // clamp: memory-safe
}

// ---------------- split-bf16 MFMA GEMM + fused alpha epilogue ----------------
// One block = 32 rows x ALL cols. 4 waves split cols; A-frags reused from
// registers across n-tiles; W packed frag-major (coalesced).
// SEL=0 reads raw x (fp32 or bf16, split on the fly); SEL=1 reads split g1.
template<int SEL>
__global__ __launch_bounds__(256) void gemm_k(const void* __restrict__ xsrc){
  const int Nc = SEL ? C_OUT : C_HID;
  const int NT = SEL ? 2 : 4;
  const unsigned short* Wh = SEL ? c_W2h : c_W1h;
  const unsigned short* Wl = SEL ? c_W2l : c_W1l;
  unsigned short* Hb = SEL ? g_h2b : g_h1b;
  float* alps = SEL ? g_alps2 : g_alps1;
  float* alpd = SEL ? g_alpd2 : g_alpd1;
  const float* aS = SEL ? c_as2f : c_as1f;
  const float* aD = SEL ? c_ad2f : c_ad1f;
  const bool isf32 = (SEL == 0) && (g_isf32 != 0);

  int wave = (int)(threadIdx.x >> 6);
  int lane = (int)(threadIdx.x & 63);
  int kgrp = lane >> 4, cl = lane & 15;
  int mbase = blockIdx.x * 32;

  f32x4 acc[2][4];
#pragma unroll
  for (int m = 0; m < 2; ++m)
#pragma unroll
    for (int n = 0; n < NT; ++n) acc[m][n] = (f32x4){0.f, 0.f, 0.f, 0.f};

  for (int kt = 0; kt < 8; ++kt){
    int kbase = kt * 32 + kgrp * 8;
    bf16x8 ah[2], al[2];
    if (SEL == 1){
#pragma unroll
      for (int m = 0; m < 2; ++m){
        size_t ai = (size_t)(mbase + m * 16 + cl) * 256 + kbase;
        ah[m] = *(const bf16x8*)(g_g1h + ai);
        al[m] = *(const bf16x8*)(g_g1l + ai);
      }
    } else if (isf32){
      const float* Xf = (const float*)xsrc;
#pragma unroll
      for (int m = 0; m < 2; ++m){
        const float4* xp = (const float4*)(Xf + (size_t)(mbase + m * 16 + cl) * 256 + kbase);
        float4 v0 = xp[0], v1 = xp[1];
        float vals[8] = {v0.x, v0.y, v0.z, v0.w, v1.x, v1.y, v1.z, v1.w};
#pragma unroll
        for (int j = 0; j < 8; ++j){
          unsigned short h = f2bf(vals[j]);
          ah[m][j] = (short)h;
          al[m][j] = (short)f2bf(vals[j] - bf2f(h));
        }
      }
    } else {  // bf16 input: lo part is zero
      const unsigned short* Xb = (const unsigned short*)xsrc;
#pragma unroll
      for (int m = 0; m < 2; ++m){
        ah[m] = *(const bf16x8*)(Xb + (size_t)(mbase + m * 16 + cl) * 256 + kbase);
        al[m] = (bf16x8){0,0,0,0,0,0,0,0};
      }
    }
#pragma unroll
    for (int nn = 0; nn < NT; ++nn){
      int nt = wave * NT + nn;
      size_t wi = ((size_t)(kt * (Nc / 16) + nt) * 64 + lane) * 8;
      bf16x8 bh = *(const bf16x8*)(Wh + wi);
      bf16x8 bl = *(const bf16x8*)(Wl + wi);
#pragma unroll
      for (int m = 0; m < 2; ++m){
        acc[m][nn] = __builtin_amdgcn_mfma_f32_16x16x32_bf16(ah[m], bh, acc[m][nn], 0, 0, 0);
        acc[m][nn] = __builtin_amdgcn_mfma_f32_16x16x32_bf16(ah[m], bl, acc[m][nn], 0, 0, 0);
        acc[m][nn] = __builtin_amdgcn_mfma_f32_16x16x32_bf16(al[m], bh, acc[m][nn], 0, 0, 0);
      }
    }
  }

  float asv[4], adv[4];
#pragma unroll
  for (int nn = 0; nn < NT; ++nn){
    int col = (wave * NT + nn) * 16 + cl;
    asv[nn] = aS[col]; adv[nn] = aD[col];
  }
#pragma unroll
  for (int m = 0; m < 2; ++m){
#pragma unroll
    for (int i = 0; i < 4; ++i){
      int row = mbase + m * 16 + kgrp * 4 + i;
      float ps = 0.f, pd = 0.f;
#pragma unroll
      for (int nn = 0; nn < NT; ++nn){
        int col = (wave * NT + nn) * 16 + cl;
        float v = acc[m][nn][i];
        Hb[(size_t)row * Nc + col] = f2bf(v);
        ps += v * asv[nn]; pd += v * adv[nn];
      }
      ps += __shfl_xor(ps, 1);  pd += __shfl_xor(pd, 1);
      ps += __shfl_xor(ps, 2);  pd += __shfl_xor(pd, 2);
      ps += __shfl_xor(ps, 4);  pd += __shfl_xor(pd, 4);
      ps += __shfl_xor(ps, 8);  pd += __shfl_xor(pd, 8);
      if (cl == 0){
        atomicAdd(&alps[row], ps);
        atomicAdd(&alpd[row], pd);
      }
    }
  }
}

// ---------------- fused softmax + aggregation: one wave per node ----------------
// R8/R12-proven structure; padded-CSR addressing (i0 = n*CAP, len = cursor[n]).
#define ACC4(p, ww) { \
  a0 += (ww) * bf2f((unsigned short)((p).x & 0xFFFFu)); \
  a1 += (ww) * bf2f((unsigned short)((p).x >> 16)); \
  a2 += (ww) * bf2f((unsigned short)((p).y & 0xFFFFu)); \
  a3 += (ww) * bf2f((unsigned short)((p).y >> 16)); }

#define ACC2(p, ww) { \
  a0 += (ww) * bf2f((unsigned short)((p) & 0xFFFFu)); \
  a1 += (ww) * bf2f((unsigned short)((p) >> 16)); }

template<int F, int SEL>
__global__ void agg_k(float* OUT){
  const unsigned short* Hb = SEL ? g_h2b : g_h1b;
  const float* bias = SEL ? c_b2f : c_b1f;
  const float* alps = SEL ? g_alps2 : g_alps1;
  const float* alpd = SEL ? g_alpd2 : g_alpd1;
  int lane = threadIdx.x & 63;
  int n = blockIdx.x * 4 + (threadIdx.x >> 6);
  int len = g_cursor[n]; if (len > CAP) len = CAP;
  int i0 = n * CAP, i1 = i0 + len;
  float adn = alpd[n];
  float dpart = 0.f;
  float a0 = 0.f, a1 = 0.f, a2 = 0.f, a3 = 0.f;
  const uint2* H2 = (const uint2*)Hb;          // F=256: lane owns 4 feats
  const unsigned int* H1 = (const unsigned int*)Hb; // F=128: lane owns 2 feats

  for (int base = i0; base < i1; base += 64){
    int nv = i1 - base; if (nv > 64) nv = 64;
    int sv = 0; float wv = 0.f;
    if (lane < nv){
      sv = g_srcidx[base + lane];
      float e = alps[sv] + adn;
      e = (e > 0.f) ? e : NEG_SLOPE * e;
      wv = __expf(e);
    }
    dpart += wv;
    int j = 0;
    for (; j + 8 <= nv; j += 8){
      int s0 = __shfl(sv, j),     s1 = __shfl(sv, j + 1);
      int s2 = __shfl(sv, j + 2), s3 = __shfl(sv, j + 3);
      int s4 = __shfl(sv, j + 4), s5 = __shfl(sv, j + 5);
      int s6 = __shfl(sv, j + 6), s7 = __shfl(sv, j + 7);
      float w0 = __shfl(wv, j),     w1 = __shfl(wv, j + 1);
      float w2 = __shfl(wv, j + 2), w3 = __shfl(wv, j + 3);
      float w4 = __shfl(wv, j + 4), w5 = __shfl(wv, j + 5);
      float w6 = __shfl(wv, j + 6), w7 = __shfl(wv, j + 7);
      if constexpr (F == 256){
        uint2 p0 = H2[(size_t)s0 * 64 + lane];
        uint2 p1 = H2[(size_t)s1 * 64 + lane];
        uint2 p2 = H2[(size_t)s2 * 64 + lane];
        uint2 p3 = H2[(size_t)s3 * 64 + lane];
        uint2 p4 = H2[(size_t)s4 * 64 + lane];
        uint2 p5 = H2[(size_t)s5 * 64 + lane];
        uint2 p6 = H2[(size_t)s6 * 64 + lane];
        uint2 p7 = H2[(size_t)s7 * 64 + lane];
        ACC4(p0, w0) ACC4(p1, w1) ACC4(p2, w2) ACC4(p3, w3)
        ACC4(p4, w4) ACC4(p5, w5) ACC4(p6, w6) ACC4(p7, w7)
      } else {
        unsigned int p0 = H1[(size_t)s0 * 64 + lane];
        unsigned int p1 = H1[(size_t)s1 * 64 + lane];
        unsigned int p2 = H1[(size_t)s2 * 64 + lane];
        unsigned int p3 = H1[(size_t)s3 * 64 + lane];
        unsigned int p4 = H1[(size_t)s4 * 64 + lane];
        unsigned int p5 = H1[(size_t)s5 * 64 + lane];
        unsigned int p6 = H1[(size_t)s6 * 64 + lane];
        unsigned int p7 = H1[(size_t)s7 * 64 + lane];
        ACC2(p0, w0) ACC2(p1, w1) ACC2(p2, w2) ACC2(p3, w3)
        ACC2(p4, w4) ACC2(p5, w5) ACC2(p6, w6) ACC2(p7, w7)
      }
    }
    for (; j + 4 <= nv; j += 4){
      int s0 = __shfl(sv, j),     s1 = __shfl(sv, j + 1);
      int s2 = __shfl(sv, j + 2), s3 = __shfl(sv, j + 3);
      float w0 = __shfl(wv, j),     w1 = __shfl(wv, j + 1);
      float w2 = __shfl(wv, j + 2), w3 = __shfl(wv, j + 3);
      if constexpr (F == 256){
        uint2 p0 = H2[(size_t)s0 * 64 + lane];
        uint2 p1 = H2[(size_t)s1 * 64 + lane];
        uint2 p2 = H2[(size_t)s2 * 64 + lane];
        uint2 p3 = H2[(size_t)s3 * 64 + lane];
        ACC4(p0, w0) ACC4(p1, w1) ACC4(p2, w2) ACC4(p3, w3)
      } else {
        unsigned int p0 = H1[(size_t)s0 * 64 + lane];
        unsigned int p1 = H1[(size_t)s1 * 64 + lane];
        unsigned int p2 = H1[(size_t)s2 * 64 + lane];
        unsigned int p3 = H1[(size_t)s3 * 64 + lane];
        ACC2(p0, w0) ACC2(p1, w1) ACC2(p2, w2) ACC2(p3, w3)
      }
    }
    for (; j < nv; ++j){
      int s = __shfl(sv, j);
      float w = __shfl(wv, j);
      if constexpr (F == 256){
        uint2 p = H2[(size_t)s * 64 + lane];
        ACC4(p, w)
      } else {
        unsigned int p = H1[(size_t)s * 64 + lane];
        ACC2(p, w)
      }
    }
  }

  float den = dpart;
#pragma unroll
  for (int o = 32; o > 0; o >>= 1) den += __shfl_xor(den, o, 64);
  float inv = 1.f / den;

  if constexpr (F == 256){
    float o0 = a0 * inv + bias[4 * lane];
    float o1 = a1 * inv + bias[4 * lane + 1];
    float o2 = a2 * inv + bias[4 * lane + 2];
    float o3 = a3 * inv + bias[4 * lane + 3];
    if (SEL == 0){
      o0 = fmaxf(o0, 0.f); o1 = fmaxf(o1, 0.f);
      o2 = fmaxf(o2, 0.f); o3 = fmaxf(o3, 0.f);
      unsigned short h0 = f2bf(o0), h1 = f2bf(o1), h2 = f2bf(o2), h3 = f2bf(o3);
      uint2 ph, pl;
      ph.x = (unsigned)h0 | ((unsigned)h1 << 16);
      ph.y = (unsigned)h2 | ((unsigned)h3 << 16);
      pl.x = (unsigned)f2bf(o0 - bf2f(h0)) | ((unsigned)f2bf(o1 - bf2f(h1)) << 16);
      pl.y = (unsigned)f2bf(o2 - bf2f(h2)) | ((unsigned)f2bf(o3 - bf2f(h3)) << 16);
      ((uint2*)g_g1h)[(size_t)n * 64 + lane] = ph;
      ((uint2*)g_g1l)[(size_t)n * 64 + lane] = pl;
    } else {
      float4 o; o.x = o0; o.y = o1; o.z = o2; o.w = o3;
      ((float4*)OUT)[(size_t)n * 64 + lane] = o;
    }
  } else {
    float o0 = a0 * inv + bias[2 * lane];
    float o1 = a1 * inv + bias[2 * lane + 1];
    if (SEL == 0){
      o0 = fmaxf(o0, 0.f); o1 = fmaxf(o1, 0.f);
      unsigned short h0 = f2bf(o0), h1 = f2bf(o1);
      ((unsigned int*)g_g1h)[(size_t)n * 64 + lane] = (unsigned)h0 | ((unsigned)h1 << 16);
      ((unsigned int*)g_g1l)[(size_t)n * 64 + lane] =
        (unsigned)f2bf(o0 - bf2f(h0)) | ((unsigned)f2bf(o1 - bf2f(h1)) << 16);
    } else {
      float2 o; o.x = o0; o.y = o1;
      ((float2*)OUT)[(size_t)n * 64 + lane] = o;
    }
  }
}

extern "C" void kernel_launch(void* const* d_in, const int* in_sizes, int n_in,
                              void* d_out, int out_size, void* d_ws, size_t ws_size,
                              hipStream_t stream){
  (void)in_sizes; (void)n_in; (void)out_size; (void)d_ws; (void)ws_size;
  const void* x  = d_in[0];
  const int*  ei = (const int*)d_in[1];
  float* out = (float*)d_out;

  Ptrs ps;
  ps.p[0] = d_in[2]; ps.p[1] = d_in[3]; ps.p[2] = d_in[4]; ps.p[3] = d_in[5];
  ps.p[4] = d_in[6]; ps.p[5] = d_in[7]; ps.p[6] = d_in[8]; ps.p[7] = d_in[9];

  prep_k<<<(PREP_T + 255) / 256, 256, 0, stream>>>((const unsigned int*)x, ei, ps);
  scatter_k<<<(E_TOT + 255) / 256, 256, 0, stream>>>(ei);

  // ---- layer 1 ----
  gemm_k<0><<<N_NODES / 32, 256, 0, stream>>>(x);
  agg_k<C_HID, 0><<<N_NODES / 4, 256, 0, stream>>>(nullptr);

  // ---- layer 2 ----
  gemm_k<1><<<N_NODES / 32, 256, 0, stream>>>(nullptr);
  agg_k<C_OUT, 1><<<N_NODES / 4, 256, 0, stream>>>(out);
}